// Round 1
// baseline (53.280 us; speedup 1.0000x reference)
//
#include <hip/hip_runtime.h>
#include <hip/hip_bf16.h>

#define BATCH 8
#define SEQ   8192
#define DIM   512

// ---------------------------------------------------------------------------
// Kernel A: segment ids. One block per batch row, 256 threads, 32 tokens each.
//
// Reference scan per step i (i = 1..SEQ-1), carry nc (int, starts 0):
//   c = tok[i]; p = tok[i-1];
//   if (36 <= c <= 41) nc = 2;
//   is_note = c < 12;
//   change  = is_note ? ((p >= 12) || (nc > 0)) : (p < 12);
//   if (is_note) nc -= 1;
// seg = inclusive cumsum of change flags (flag[0] = 0).
//
// nc transform over a chunk is (has_reset, val): T(nc) = reset ? val : nc+val.
// Applied to nc=0 both cases give `val`, so the cross-chunk scan only needs
// compose((A earlier),(B later)) = B.reset ? B : (A.reset, A.val + B.val).
// ---------------------------------------------------------------------------
#define THREADS_A 256
#define CHUNK_A   (SEQ / THREADS_A)   // 32

__global__ __launch_bounds__(THREADS_A)
void seg_kernel(const int* __restrict__ tok, int* __restrict__ seg) {
    const int b   = blockIdx.x;
    const int tid = threadIdx.x;
    const int* t  = tok + (size_t)b * SEQ;
    int*       sg = seg + (size_t)b * SEQ;

    const int start = tid * CHUNK_A;
    const int end   = start + CHUNK_A;
    const int lo    = (start < 1) ? 1 : start;   // step i starts at 1

    // ---- pass 1: per-chunk nc transform --------------------------------
    int reset = 0, val = 0;
    for (int i = lo; i < end; ++i) {
        int c = t[i];
        if (c >= 36 && c <= 41) { reset = 1; val = 2; }
        if (c < 12) val -= 1;
    }

    __shared__ int s_val[THREADS_A];
    __shared__ int s_rst[THREADS_A];
    s_val[tid] = val;
    s_rst[tid] = reset;
    __syncthreads();

    // inclusive Hillis-Steele scan of the (reset,val) monoid
    for (int off = 1; off < THREADS_A; off <<= 1) {
        int pv = 0, pr = 0;
        if (tid >= off) { pv = s_val[tid - off]; pr = s_rst[tid - off]; }
        __syncthreads();
        if (tid >= off && !s_rst[tid]) {
            s_val[tid] += pv;
            s_rst[tid]  = pr;
        }
        __syncthreads();
    }

    const int nc_entry = (tid == 0) ? 0 : s_val[tid - 1];
    __syncthreads();   // about to reuse s_val

    // ---- pass 2: count flags in chunk with known entry nc ---------------
    int nc = nc_entry;
    int total = 0;
    for (int i = lo; i < end; ++i) {
        int c = t[i];
        int p = t[i - 1];
        if (c >= 36 && c <= 41) nc = 2;
        bool is_note = (c < 12);
        int f = is_note ? (int)((p >= 12) || (nc > 0)) : (int)(p < 12);
        if (is_note) nc -= 1;
        total += f;
    }

    s_val[tid] = total;
    __syncthreads();
    for (int off = 1; off < THREADS_A; off <<= 1) {
        int pv = 0;
        if (tid >= off) pv = s_val[tid - off];
        __syncthreads();
        if (tid >= off) s_val[tid] += pv;
        __syncthreads();
    }
    int run = (tid == 0) ? 0 : s_val[tid - 1];

    // ---- pass 3: recompute flags, write inclusive cumsum ----------------
    nc = nc_entry;
    if (start == 0) sg[0] = 0;   // flag[0] = 0
    for (int i = lo; i < end; ++i) {
        int c = t[i];
        int p = t[i - 1];
        if (c >= 36 && c <= 41) nc = 2;
        bool is_note = (c < 12);
        int f = is_note ? (int)((p >= 12) || (nc > 0)) : (int)(p < 12);
        if (is_note) nc -= 1;
        run += f;
        sg[i] = run;
    }
}

// ---------------------------------------------------------------------------
// Kernel B: out[row, d] = emb[tok[row], d] * sqrt(512) + pe(seg[row], d)
// pe(pos, 2k)   = sin(pos * div[k]),  pe(pos, 2k+1) = cos(pos * div[k])
// div[k] = exp(-2k * ln(10000)/512), k = 0..255  (LDS table, 1 expf/thread)
//
// One thread = one float4 (4 consecutive d). 128 threads per 512-float row.
// v_sin/v_cos take revolutions; explicit fract range reduction (angles up to
// ~8191 rad = ~1304 revolutions exceed the HW-safe domain).
// ---------------------------------------------------------------------------
__global__ __launch_bounds__(256)
void out_kernel(const int*   __restrict__ tok,
                const int*   __restrict__ seg,
                const float* __restrict__ emb,
                float*       __restrict__ out) {
    __shared__ float s_div[256];
    const int tid = threadIdx.x;
    // div[k] = exp(-0.035977892078f * k)
    s_div[tid] = expf(-0.035977892078031965f * (float)tid);
    __syncthreads();

    const long long g   = (long long)blockIdx.x * 256 + tid;
    const int  row = (int)(g >> 7);          // b*SEQ + s
    const int  d0  = ((int)g & 127) << 2;    // 0..508, step 4

    const int   token = tok[row];
    const float segf  = (float)seg[row];

    const float4 e = *reinterpret_cast<const float4*>(emb + (size_t)token * DIM + d0);

    const int   k0   = d0 >> 1;              // even-d pair index
    const float div0 = s_div[k0];
    const float div1 = s_div[k0 + 1];

    const float INV2PI = 0.15915494309189535f;
    float r0 = segf * div0 * INV2PI; r0 -= floorf(r0);
    float r1 = segf * div1 * INV2PI; r1 -= floorf(r1);

    const float s0 = __builtin_amdgcn_sinf(r0);
    const float c0 = __builtin_amdgcn_cosf(r0);
    const float s1 = __builtin_amdgcn_sinf(r1);
    const float c1 = __builtin_amdgcn_cosf(r1);

    const float SCALE = 22.62741699796952f;  // sqrt(512)
    float4 o;
    o.x = e.x * SCALE + s0;
    o.y = e.y * SCALE + c0;
    o.z = e.z * SCALE + s1;
    o.w = e.w * SCALE + c1;
    *reinterpret_cast<float4*>(out + (size_t)row * DIM + d0) = o;
}

extern "C" void kernel_launch(void* const* d_in, const int* in_sizes, int n_in,
                              void* d_out, int out_size, void* d_ws, size_t ws_size,
                              hipStream_t stream) {
    const int*   tok = (const int*)d_in[0];     // (BATCH, SEQ) int32
    const float* emb = (const float*)d_in[1];   // (VOCAB, DIM) f32
    float*       out = (float*)d_out;           // (BATCH, SEQ, DIM) f32
    int*         seg = (int*)d_ws;              // (BATCH, SEQ) int32 scratch

    seg_kernel<<<BATCH, THREADS_A, 0, stream>>>(tok, seg);

    const long long total_f4 = (long long)BATCH * SEQ * DIM / 4;  // 8,388,608
    const int blocks = (int)(total_f4 / 256);                      // 32,768
    out_kernel<<<blocks, 256, 0, stream>>>(tok, seg, emb, out);
}